// Round 16
// baseline (236.201 us; speedup 1.0000x reference)
//
#include <hip/hip_runtime.h>
#include <hip/hip_bf16.h>
#include <cstddef>

#define GAT_B 16
#define GAT_N 2048
#define GAT_D 128
#define GAT_ROWS (GAT_B * GAT_N)
#define CH 256          // position-chunks per batch
#define CL 8            // positions per chunk
#define GAT_ALPHA 0.2f

typedef __attribute__((ext_vector_type(8))) short short8v;  // 8 bf16 (4 VGPRs)
typedef __attribute__((ext_vector_type(4))) float f32x4;

__device__ __forceinline__ void cvt_hilo(float x, unsigned short& hi, unsigned short& lo) {
  union { float f; unsigned u; } a;
  a.f = x;
  hi = (unsigned short)(a.u >> 16);
  union { unsigned u; float f; } b;
  b.u = (unsigned)hi << 16;
  union { float f; unsigned u; } c;
  c.f = x - b.f;
  lo = (unsigned short)(c.u >> 16);
}

// ---------------------------------------------------------------------------
// K1: h = x @ W via MFMA bf16 3-term split (x_hi*W_hi + x_lo*W_hi + x_hi*W_lo).
// 512 blocks x 256 threads (4 waves). Block tile 64 rows x 128 cols; wave =
// 64 rows x 32 cols. LDS 32KB (x hi/lo, XOR-swizzled). W read directly from
// global fp32 (L2-resident), converted in registers. [unchanged from R14]
// ---------------------------------------------------------------------------
__global__ __launch_bounds__(256) void k1_gemm(const float* __restrict__ x,
                                               const float* __restrict__ W,
                                               const float* __restrict__ aa,
                                               float* __restrict__ h,
                                               float* __restrict__ s1part,
                                               float* __restrict__ s2part) {
  __shared__ unsigned short xH[64 * 128];  // 16KB, [row][slot^row&7]
  __shared__ unsigned short xL[64 * 128];  // 16KB
  const int tid = threadIdx.x;
  const int row0 = blockIdx.x * 64;

#pragma unroll
  for (int p = 0; p < 8; ++p) {
    const int row = p * 8 + (tid >> 5);
    const int f4 = tid & 31;
    const float4 v = ((const float4*)(x + (size_t)(row0 + row) * GAT_D))[f4];
    unsigned short h0, h1, h2, h3, l0, l1, l2, l3;
    cvt_hilo(v.x, h0, l0);
    cvt_hilo(v.y, h1, l1);
    cvt_hilo(v.z, h2, l2);
    cvt_hilo(v.w, h3, l3);
    const int slot = (f4 >> 1) ^ (row & 7);
    const int base = row * 128 + slot * 8 + (f4 & 1) * 4;
    *(ushort4*)&xH[base] = make_ushort4(h0, h1, h2, h3);
    *(ushort4*)&xL[base] = make_ushort4(l0, l1, l2, l3);
  }

  const int w = tid >> 6, l = tid & 63;
  const int wc0 = w * 32;
  const int g = l >> 4, c16 = l & 15;

  short8v bh[4][2], bl[4][2];
#pragma unroll
  for (int ks = 0; ks < 4; ++ks)
#pragma unroll
    for (int nt = 0; nt < 2; ++nt) {
      const int n = wc0 + nt * 16 + c16;
#pragma unroll
      for (int j = 0; j < 8; ++j) {
        unsigned short hi, lo;
        cvt_hilo(W[(ks * 32 + g * 8 + j) * 128 + n], hi, lo);
        bh[ks][nt][j] = (short)hi;
        bl[ks][nt][j] = (short)lo;
      }
    }

  __syncthreads();

  f32x4 acc[4][2];
#pragma unroll
  for (int mt = 0; mt < 4; ++mt)
#pragma unroll
    for (int nt = 0; nt < 2; ++nt) acc[mt][nt] = (f32x4)(0.f);

#pragma unroll
  for (int ks = 0; ks < 4; ++ks) {
    short8v ah[4], al[4];
#pragma unroll
    for (int mt = 0; mt < 4; ++mt) {
      const int row = mt * 16 + c16;
      const int ai = row * 128 + (((ks * 4 + g) ^ (row & 7)) * 8);
      ah[mt] = *(const short8v*)&xH[ai];
      al[mt] = *(const short8v*)&xL[ai];
    }
#pragma unroll
    for (int mt = 0; mt < 4; ++mt) {
#pragma unroll
      for (int nt = 0; nt < 2; ++nt) {
        acc[mt][nt] = __builtin_amdgcn_mfma_f32_16x16x32_bf16(ah[mt], bh[ks][nt], acc[mt][nt], 0, 0, 0);
        acc[mt][nt] = __builtin_amdgcn_mfma_f32_16x16x32_bf16(al[mt], bh[ks][nt], acc[mt][nt], 0, 0, 0);
        acc[mt][nt] = __builtin_amdgcn_mfma_f32_16x16x32_bf16(ah[mt], bl[ks][nt], acc[mt][nt], 0, 0, 0);
      }
    }
  }

#pragma unroll
  for (int mt = 0; mt < 4; ++mt)
#pragma unroll
    for (int nt = 0; nt < 2; ++nt)
#pragma unroll
      for (int j = 0; j < 4; ++j)
        h[(size_t)(row0 + mt * 16 + g * 4 + j) * GAT_D + wc0 + nt * 16 + c16] =
            acc[mt][nt][j];

  float a1v[2], a2v[2];
#pragma unroll
  for (int nt = 0; nt < 2; ++nt) {
    a1v[nt] = aa[wc0 + nt * 16 + c16];
    a2v[nt] = aa[128 + wc0 + nt * 16 + c16];
  }
#pragma unroll
  for (int mt = 0; mt < 4; ++mt) {
#pragma unroll
    for (int j = 0; j < 4; ++j) {
      float t1 = acc[mt][0][j] * a1v[0] + acc[mt][1][j] * a1v[1];
      float t2 = acc[mt][0][j] * a2v[0] + acc[mt][1][j] * a2v[1];
#pragma unroll
      for (int off = 1; off < 16; off <<= 1) {
        t1 += __shfl_xor(t1, off);
        t2 += __shfl_xor(t2, off);
      }
      if (c16 == 0) {
        const int row = row0 + mt * 16 + g * 4 + j;
        s1part[w * GAT_ROWS + row] = t1;
        s2part[w * GAT_ROWS + row] = t2;
      }
    }
  }
}

// ---------------------------------------------------------------------------
// K2: 32 blocks (2 per batch), 1024 threads. HYBRID bitonic (k<=128 in
// registers via shfl_xor; k>=256 LDS for j>=128 + register tail).
//  even block: sort s2 -> idxs + exp weights wA/wP; den scans stay in LDS;
//              per-row NATURAL-order binary search p + c1/c2 (overlaps the
//              odd block's s1 sort; s2s/preDen/sufDen globals deleted).
//  odd block:  sort key=-s1 -> rids only (k5's processing order).
// ---------------------------------------------------------------------------
__global__ __launch_bounds__(1024) void k2_sort(const float* __restrict__ s1part,
                                                const float* __restrict__ s2part,
                                                int* __restrict__ idxs,
                                                int* __restrict__ rids,
                                                float* __restrict__ wA,
                                                float* __restrict__ wP,
                                                int* __restrict__ pNat,
                                                float* __restrict__ c1,
                                                float* __restrict__ c2) {
  __shared__ float v[2048];
  __shared__ int id[2048];
  __shared__ float denA[2048];
  __shared__ float denP[2048];
  __shared__ float wtotA[16];
  __shared__ float wtotP[16];
  const int tid = threadIdx.x;
  const int b = blockIdx.x >> 1;
  const int half = blockIdx.x & 1;
  const int i0 = tid, i1 = tid + 1024;
  const float* src = (half == 0) ? s2part : s1part;
  {
    const int r0 = b * GAT_N + i0, r1 = b * GAT_N + i1;
    float v0 = src[r0] + src[GAT_ROWS + r0] + src[2 * GAT_ROWS + r0] + src[3 * GAT_ROWS + r0];
    float v1 = src[r1] + src[GAT_ROWS + r1] + src[2 * GAT_ROWS + r1] + src[3 * GAT_ROWS + r1];
    if (half == 1) {
      v0 = -v0;
      v1 = -v1;
    }
    v[i0] = v0;
    v[i1] = v1;
  }
  __syncthreads();

  const int lane = tid & 63;
  const int e0 = ((tid >> 6) << 7) + lane * 2;  // wave-run base + 2*lane
  const int e1 = e0 + 1;
  float va = v[e0], vb = v[e1];
  int ida = e0, idb = e1;

  auto lanex = [&](int k, int j) {
    const int jl = j >> 1;
    const bool dir = (e0 & k) == 0;
    const bool lower = (lane & jl) == 0;
    const bool keepMax = lower ^ dir;
    {
      const float ov = __shfl_xor(va, jl);
      const int oid = __shfl_xor(ida, jl);
      const bool ogt = (ov > va) || (ov == va && oid > ida);
      if (ogt == keepMax) { va = ov; ida = oid; }
    }
    {
      const float ov = __shfl_xor(vb, jl);
      const int oid = __shfl_xor(idb, jl);
      const bool ogt = (ov > vb) || (ov == vb && oid > idb);
      if (ogt == keepMax) { vb = ov; idb = oid; }
    }
  };
  auto pairx = [&](int k) {
    const bool dir = (e0 & k) == 0;
    const bool bgt = (vb > va) || (vb == va && idb > ida);
    if (bgt != dir) {
      const float tv = va; va = vb; vb = tv;
      const int ti = ida; ida = idb; idb = ti;
    }
  };

#pragma unroll
  for (int k = 2; k <= 128; k <<= 1) {
#pragma unroll
    for (int j = k >> 1; j >= 2; j >>= 1) lanex(k, j);
    pairx(k);
  }
  v[e0] = va; id[e0] = ida;
  v[e1] = vb; id[e1] = idb;
  __syncthreads();

  for (int k = 256; k <= 2048; k <<= 1) {
    for (int j = k >> 1; j >= 128; j >>= 1) {
      const int i = ((tid & ~(j - 1)) << 1) | (tid & (j - 1));
      const int ixj = i | j;
      const bool up = (i & k) == 0;
      const float x0 = v[i], x1 = v[ixj];
      if (up ? (x0 > x1) : (x0 < x1)) {
        v[i] = x1;
        v[ixj] = x0;
        const int ti = id[i];
        id[i] = id[ixj];
        id[ixj] = ti;
      }
      __syncthreads();
    }
    va = v[e0]; ida = id[e0];
    vb = v[e1]; idb = id[e1];
#pragma unroll
    for (int j = 64; j >= 2; j >>= 1) lanex(k, j);
    pairx(k);
    v[e0] = va; id[e0] = ida;
    v[e1] = vb; id[e1] = idb;
    __syncthreads();
  }

  if (half == 1) {
    rids[b * GAT_N + i0] = id[i0];
    rids[b * GAT_N + i1] = id[i1];
    return;
  }
  idxs[b * GAT_N + i0] = id[i0];
  idxs[b * GAT_N + i1] = id[i1];

  // den scans (LDS-only) + sorted exp weights to global
  const int w = tid >> 6;
  const float aL = __expf(GAT_ALPHA * v[2 * tid]);
  const float aR = __expf(GAT_ALPHA * v[2 * tid + 1]);
  const float pL = __expf(v[2047 - 2 * tid]);
  const float pR = __expf(v[2046 - 2 * tid]);
  wA[b * GAT_N + 2 * tid] = aL;
  wA[b * GAT_N + 2 * tid + 1] = aR;
  wP[b * GAT_N + 2047 - 2 * tid] = pL;
  wP[b * GAT_N + 2046 - 2 * tid] = pR;
  float sA = aL + aR, sP = pL + pR;
#pragma unroll
  for (int off = 1; off < 64; off <<= 1) {
    const float tA = __shfl_up(sA, off);
    const float tP = __shfl_up(sP, off);
    if (lane >= off) {
      sA += tA;
      sP += tP;
    }
  }
  if (lane == 63) {
    wtotA[w] = sA;
    wtotP[w] = sP;
  }
  __syncthreads();
  float offA = 0.f, offP = 0.f;
  for (int ww = 0; ww < w; ++ww) {
    offA += wtotA[ww];
    offP += wtotP[ww];
  }
  const float inclA = offA + sA;
  const float inclP = offP + sP;
  denA[2 * tid] = inclA - aR;
  denA[2 * tid + 1] = inclA;
  denP[2047 - 2 * tid] = inclP - pR;
  denP[2046 - 2 * tid] = inclP;
  __syncthreads();

  // per-row prep in NATURAL order against LDS v/denA/denP
#pragma unroll
  for (int rr = 0; rr < 2; ++rr) {
    const int j = tid + rr * 1024;
    const int r = b * GAT_N + j;
    const float s1v = s1part[r] + s1part[GAT_ROWS + r] + s1part[2 * GAT_ROWS + r] +
                      s1part[3 * GAT_ROWS + r];
    const float tt = -s1v;
    int lo = 0, hi = GAT_N;
    while (lo < hi) {
      const int mid = (lo + hi) >> 1;
      if (v[mid] < tt)
        lo = mid + 1;
      else
        hi = mid;
    }
    const float e1 = __expf(s1v), e2 = __expf(GAT_ALPHA * s1v);
    float den = 0.f;
    if (lo < GAT_N) den += e1 * denP[lo];
    if (lo > 0) den += e2 * denA[lo - 1];
    const float inv = 1.f / den;
    pNat[r] = lo;
    c1[r] = e1 * inv;
    c2[r] = e2 * inv;
  }
}

// ---------------------------------------------------------------------------
// K3: permute h into sorted order (hs[q] = h[idx[q]]) + CL=8 chunk partials,
// float2-wide (wave = one chunk, lane = 8B). 2048 blocks x 128 threads.
// FUSED TAIL (replaces k3b): last block of each batch (per-batch atomic
// counter, threadfence) runs the 256-chunk exclusive base scans -- wave 0
// ascending (A), wave 1 descending (P). Counters zeroed via hipMemsetAsync
// each call (replay-safe).
// ---------------------------------------------------------------------------
__global__ __launch_bounds__(128) void k3_permute(const float* __restrict__ h,
                                                  const int* __restrict__ idxs,
                                                  const float* __restrict__ wA,
                                                  const float* __restrict__ wP,
                                                  float* __restrict__ hs,
                                                  float* __restrict__ partA,
                                                  float* __restrict__ partP,
                                                  float* __restrict__ baseA,
                                                  float* __restrict__ baseP,
                                                  unsigned* __restrict__ counters) {
  const int b = blockIdx.x >> 7, cc = blockIdx.x & 127;
  const int t = threadIdx.x;
  const int w = t >> 6, l = t & 63;
  const int c = cc * 2 + w;  // each wave owns one chunk
  const int q0 = c * CL;
  const int* idxb = idxs + b * GAT_N;
  const float2* hb2 = (const float2*)(h + (size_t)b * GAT_N * GAT_D);
  float2* hs2 = (float2*)(hs + (size_t)b * GAT_N * GAT_D);
  float2 accA = make_float2(0.f, 0.f), accP = make_float2(0.f, 0.f);
#pragma unroll
  for (int qq = 0; qq < CL; ++qq) {
    const int q = q0 + qq;
    const int j = idxb[q];
    const float2 hv = hb2[(size_t)j * 64 + l];
    hs2[(size_t)q * 64 + l] = hv;
    const float wa = wA[b * GAT_N + q];
    const float wp = wP[b * GAT_N + q];
    accA.x = fmaf(wa, hv.x, accA.x);
    accA.y = fmaf(wa, hv.y, accA.y);
    accP.x = fmaf(wp, hv.x, accP.x);
    accP.y = fmaf(wp, hv.y, accP.y);
  }
  ((float2*)partA)[(size_t)(b * CH + c) * 64 + l] = accA;
  ((float2*)partP)[(size_t)(b * CH + c) * 64 + l] = accP;

  // ---- fused base scan: last block of this batch ----
  __threadfence();
  __shared__ int lastFlag;
  if (t == 0) lastFlag = (atomicAdd(&counters[b], 1u) == 127u) ? 1 : 0;
  __syncthreads();
  if (!lastFlag) return;
  __threadfence();
  const float2* pA2 = (const float2*)partA + (size_t)b * CH * 64;
  const float2* pP2 = (const float2*)partP + (size_t)b * CH * 64;
  float2* bA2 = (float2*)baseA + (size_t)b * (CH + 1) * 64;
  float2* bP2 = (float2*)baseP + (size_t)b * CH * 64;
  if (w == 0) {
    float2 run = make_float2(0.f, 0.f);
#pragma unroll 8
    for (int ci = 0; ci < CH; ++ci) {
      bA2[(size_t)ci * 64 + l] = run;
      const float2 p = pA2[(size_t)ci * 64 + l];
      run.x += p.x;
      run.y += p.y;
    }
    bA2[(size_t)CH * 64 + l] = run;
  } else {
    float2 run = make_float2(0.f, 0.f);
#pragma unroll 8
    for (int ci = CH - 1; ci >= 0; --ci) {
      bP2[(size_t)ci * 64 + l] = run;
      const float2 p = pP2[(size_t)ci * 64 + l];
      run.x += p.x;
      run.y += p.y;
    }
  }
}

// ---------------------------------------------------------------------------
// K5: one wave per row in s1-sorted order (p-locality), 256-thread blocks
// (R14 shape). rid = rids[jr]; p/c1/c2 natural-indexed (L2-hot broadcast).
// Chunk base + <=8-step within-chunk float2 cumsum over streaming hs,
// combine, relu, write out[rid].
// ---------------------------------------------------------------------------
__global__ __launch_bounds__(256) void k5_out(const float* __restrict__ hs,
                                              const float* __restrict__ wA,
                                              const float* __restrict__ wP,
                                              const float* __restrict__ baseA,
                                              const float* __restrict__ baseP,
                                              const int* __restrict__ pNat,
                                              const float* __restrict__ c1,
                                              const float* __restrict__ c2,
                                              const int* __restrict__ rids,
                                              float* __restrict__ out) {
  const int wave = threadIdx.x >> 6, lane = threadIdx.x & 63;
  const int j = blockIdx.x * 4 + wave;  // sorted row index
  const int b = j >> 11;
  const int jr = b * GAT_N + (j & 2047);
  const int rid = rids[jr];
  const int nr = b * GAT_N + rid;
  const int p = pNat[nr];
  const float cc1 = c1[nr], cc2 = c2[nr];
  const float2* hs2 = (const float2*)(hs + (size_t)b * GAT_N * GAT_D);
  const float* wAb = wA + b * GAT_N;
  const float* wPb = wP + b * GAT_N;

  const int cA = p >> 3;
  float2 accA = ((const float2*)(baseA + (size_t)(b * (CH + 1) + cA) * GAT_D))[lane];
#pragma unroll 4
  for (int q = cA * CL; q < p; ++q) {
    const float w = wAb[q];
    const float2 hv = hs2[(size_t)q * 64 + lane];
    accA.x = fmaf(w, hv.x, accA.x);
    accA.y = fmaf(w, hv.y, accA.y);
  }

  const int pP = p < GAT_N ? p : GAT_N - 1;
  const int cP = pP >> 3;
  float2 accP = ((const float2*)(baseP + (size_t)(b * CH + cP) * GAT_D))[lane];
  const int qend = cP * CL + CL;
#pragma unroll 4
  for (int q = p; q < qend; ++q) {
    const float w = wPb[q];
    const float2 hv = hs2[(size_t)q * 64 + lane];
    accP.x = fmaf(w, hv.x, accP.x);
    accP.y = fmaf(w, hv.y, accP.y);
  }

  const float vx = cc2 * accA.x + cc1 * accP.x;
  const float vy = cc2 * accA.y + cc1 * accP.y;
  ((float2*)out)[(size_t)nr * 64 + lane] =
      make_float2(fmaxf(vx, 0.f), fmaxf(vy, 0.f));
}

extern "C" void kernel_launch(void* const* d_in, const int* in_sizes, int n_in,
                              void* d_out, int out_size, void* d_ws, size_t ws_size,
                              hipStream_t stream) {
  (void)in_sizes;
  (void)n_in;
  (void)out_size;
  (void)ws_size;
  const float* x = (const float*)d_in[0];
  const float* W = (const float*)d_in[1];
  const float* a = (const float*)d_in[2];
  float* out = (float*)d_out;
  float* wsf = (float*)d_ws;

  const size_t HN = (size_t)GAT_ROWS * GAT_D;
  size_t o = 0;
  float* s1part = wsf + o;   o += 4 * GAT_ROWS;
  float* s2part = wsf + o;   o += 4 * GAT_ROWS;
  int* idxs = (int*)(wsf + o); o += GAT_ROWS;
  int* rids = (int*)(wsf + o); o += GAT_ROWS;
  float* wAr = wsf + o;      o += GAT_ROWS;
  float* wPr = wsf + o;      o += GAT_ROWS;
  int* pNat = (int*)(wsf + o); o += GAT_ROWS;
  float* c1 = wsf + o;       o += GAT_ROWS;
  float* c2 = wsf + o;       o += GAT_ROWS;
  float* partA = wsf + o;    o += (size_t)GAT_B * CH * GAT_D;
  float* partP = wsf + o;    o += (size_t)GAT_B * CH * GAT_D;
  float* baseA = wsf + o;    o += (size_t)GAT_B * (CH + 1) * GAT_D;
  float* baseP = wsf + o;    o += (size_t)GAT_B * CH * GAT_D;
  unsigned* counters = (unsigned*)(wsf + o); o += 16;
  float* h = wsf + o;        o += HN;
  float* hs = wsf + o;       o += HN;

  hipMemsetAsync(counters, 0, GAT_B * sizeof(unsigned), stream);
  k1_gemm<<<512, 256, 0, stream>>>(x, W, a, h, s1part, s2part);
  k2_sort<<<2 * GAT_B, 1024, 0, stream>>>(s1part, s2part, idxs, rids, wAr, wPr,
                                          pNat, c1, c2);
  k3_permute<<<GAT_B * 128, 128, 0, stream>>>(h, idxs, wAr, wPr, hs, partA, partP,
                                              baseA, baseP, counters);
  k5_out<<<GAT_ROWS / 4, 256, 0, stream>>>(hs, wAr, wPr, baseA, baseP, pNat, c1, c2,
                                           rids, out);
}

// Round 17
// 66.863 us; speedup vs baseline: 3.5326x; 3.5326x over previous
//
#include <hip/hip_runtime.h>
#include <hip/hip_bf16.h>
#include <cstddef>

#define GAT_B 16
#define GAT_N 2048
#define GAT_D 128
#define GAT_ROWS (GAT_B * GAT_N)
#define CH 256          // position-chunks per batch
#define CL 8            // positions per chunk
#define GAT_ALPHA 0.2f

typedef __attribute__((ext_vector_type(8))) short short8v;  // 8 bf16 (4 VGPRs)
typedef __attribute__((ext_vector_type(4))) float f32x4;

__device__ __forceinline__ void cvt_hilo(float x, unsigned short& hi, unsigned short& lo) {
  union { float f; unsigned u; } a;
  a.f = x;
  hi = (unsigned short)(a.u >> 16);
  union { unsigned u; float f; } b;
  b.u = (unsigned)hi << 16;
  union { float f; unsigned u; } c;
  c.f = x - b.f;
  lo = (unsigned short)(c.u >> 16);
}

// ---------------------------------------------------------------------------
// K1: h = x @ W via MFMA bf16 3-term split (x_hi*W_hi + x_lo*W_hi + x_hi*W_lo).
// 512 blocks x 256 threads (4 waves). Block tile 64 rows x 128 cols; wave =
// 64 rows x 32 cols. LDS 32KB (x hi/lo, XOR-swizzled). W read directly from
// global fp32 (L2-resident), converted in registers. [R14, banked]
// ---------------------------------------------------------------------------
__global__ __launch_bounds__(256) void k1_gemm(const float* __restrict__ x,
                                               const float* __restrict__ W,
                                               const float* __restrict__ aa,
                                               float* __restrict__ h,
                                               float* __restrict__ s1part,
                                               float* __restrict__ s2part) {
  __shared__ unsigned short xH[64 * 128];  // 16KB, [row][slot^row&7]
  __shared__ unsigned short xL[64 * 128];  // 16KB
  const int tid = threadIdx.x;
  const int row0 = blockIdx.x * 64;

#pragma unroll
  for (int p = 0; p < 8; ++p) {
    const int row = p * 8 + (tid >> 5);
    const int f4 = tid & 31;
    const float4 v = ((const float4*)(x + (size_t)(row0 + row) * GAT_D))[f4];
    unsigned short h0, h1, h2, h3, l0, l1, l2, l3;
    cvt_hilo(v.x, h0, l0);
    cvt_hilo(v.y, h1, l1);
    cvt_hilo(v.z, h2, l2);
    cvt_hilo(v.w, h3, l3);
    const int slot = (f4 >> 1) ^ (row & 7);
    const int base = row * 128 + slot * 8 + (f4 & 1) * 4;
    *(ushort4*)&xH[base] = make_ushort4(h0, h1, h2, h3);
    *(ushort4*)&xL[base] = make_ushort4(l0, l1, l2, l3);
  }

  const int w = tid >> 6, l = tid & 63;
  const int wc0 = w * 32;
  const int g = l >> 4, c16 = l & 15;

  short8v bh[4][2], bl[4][2];
#pragma unroll
  for (int ks = 0; ks < 4; ++ks)
#pragma unroll
    for (int nt = 0; nt < 2; ++nt) {
      const int n = wc0 + nt * 16 + c16;
#pragma unroll
      for (int j = 0; j < 8; ++j) {
        unsigned short hi, lo;
        cvt_hilo(W[(ks * 32 + g * 8 + j) * 128 + n], hi, lo);
        bh[ks][nt][j] = (short)hi;
        bl[ks][nt][j] = (short)lo;
      }
    }

  __syncthreads();

  f32x4 acc[4][2];
#pragma unroll
  for (int mt = 0; mt < 4; ++mt)
#pragma unroll
    for (int nt = 0; nt < 2; ++nt) acc[mt][nt] = (f32x4)(0.f);

#pragma unroll
  for (int ks = 0; ks < 4; ++ks) {
    short8v ah[4], al[4];
#pragma unroll
    for (int mt = 0; mt < 4; ++mt) {
      const int row = mt * 16 + c16;
      const int ai = row * 128 + (((ks * 4 + g) ^ (row & 7)) * 8);
      ah[mt] = *(const short8v*)&xH[ai];
      al[mt] = *(const short8v*)&xL[ai];
    }
#pragma unroll
    for (int mt = 0; mt < 4; ++mt) {
#pragma unroll
      for (int nt = 0; nt < 2; ++nt) {
        acc[mt][nt] = __builtin_amdgcn_mfma_f32_16x16x32_bf16(ah[mt], bh[ks][nt], acc[mt][nt], 0, 0, 0);
        acc[mt][nt] = __builtin_amdgcn_mfma_f32_16x16x32_bf16(al[mt], bh[ks][nt], acc[mt][nt], 0, 0, 0);
        acc[mt][nt] = __builtin_amdgcn_mfma_f32_16x16x32_bf16(ah[mt], bl[ks][nt], acc[mt][nt], 0, 0, 0);
      }
    }
  }

#pragma unroll
  for (int mt = 0; mt < 4; ++mt)
#pragma unroll
    for (int nt = 0; nt < 2; ++nt)
#pragma unroll
      for (int j = 0; j < 4; ++j)
        h[(size_t)(row0 + mt * 16 + g * 4 + j) * GAT_D + wc0 + nt * 16 + c16] =
            acc[mt][nt][j];

  float a1v[2], a2v[2];
#pragma unroll
  for (int nt = 0; nt < 2; ++nt) {
    a1v[nt] = aa[wc0 + nt * 16 + c16];
    a2v[nt] = aa[128 + wc0 + nt * 16 + c16];
  }
#pragma unroll
  for (int mt = 0; mt < 4; ++mt) {
#pragma unroll
    for (int j = 0; j < 4; ++j) {
      float t1 = acc[mt][0][j] * a1v[0] + acc[mt][1][j] * a1v[1];
      float t2 = acc[mt][0][j] * a2v[0] + acc[mt][1][j] * a2v[1];
#pragma unroll
      for (int off = 1; off < 16; off <<= 1) {
        t1 += __shfl_xor(t1, off);
        t2 += __shfl_xor(t2, off);
      }
      if (c16 == 0) {
        const int row = row0 + mt * 16 + g * 4 + j;
        s1part[w * GAT_ROWS + row] = t1;
        s2part[w * GAT_ROWS + row] = t2;
      }
    }
  }
}

// ---------------------------------------------------------------------------
// K2: 32 blocks (2 per batch), 1024 threads. HYBRID bitonic (k<=128 in
// registers via shfl_xor; k>=256 LDS for j>=128 + register tail).
//  even block: sort s2 -> s2s/idxs, exp weights wA/wP, + den scans.
//  odd block:  sort key=-s1 -> s1s (desc) / rids.  [R14, banked]
// ---------------------------------------------------------------------------
__global__ __launch_bounds__(1024) void k2_sort(const float* __restrict__ s1part,
                                                const float* __restrict__ s2part,
                                                float* __restrict__ s2s,
                                                int* __restrict__ idxs,
                                                float* __restrict__ s1s,
                                                int* __restrict__ rids,
                                                float* __restrict__ wA,
                                                float* __restrict__ wP,
                                                float* __restrict__ preDenA,
                                                float* __restrict__ sufDenP) {
  __shared__ float v[2048];
  __shared__ int id[2048];
  __shared__ float wtotA[16];
  __shared__ float wtotP[16];
  const int tid = threadIdx.x;
  const int b = blockIdx.x >> 1;
  const int half = blockIdx.x & 1;
  const int i0 = tid, i1 = tid + 1024;
  const float* src = (half == 0) ? s2part : s1part;
  {
    const int r0 = b * GAT_N + i0, r1 = b * GAT_N + i1;
    float v0 = src[r0] + src[GAT_ROWS + r0] + src[2 * GAT_ROWS + r0] + src[3 * GAT_ROWS + r0];
    float v1 = src[r1] + src[GAT_ROWS + r1] + src[2 * GAT_ROWS + r1] + src[3 * GAT_ROWS + r1];
    if (half == 1) {
      v0 = -v0;
      v1 = -v1;
    }
    v[i0] = v0;
    v[i1] = v1;
  }
  __syncthreads();

  const int lane = tid & 63;
  const int e0 = ((tid >> 6) << 7) + lane * 2;  // wave-run base + 2*lane
  const int e1 = e0 + 1;
  float va = v[e0], vb = v[e1];
  int ida = e0, idb = e1;

  auto lanex = [&](int k, int j) {
    const int jl = j >> 1;
    const bool dir = (e0 & k) == 0;
    const bool lower = (lane & jl) == 0;
    const bool keepMax = lower ^ dir;
    {
      const float ov = __shfl_xor(va, jl);
      const int oid = __shfl_xor(ida, jl);
      const bool ogt = (ov > va) || (ov == va && oid > ida);
      if (ogt == keepMax) { va = ov; ida = oid; }
    }
    {
      const float ov = __shfl_xor(vb, jl);
      const int oid = __shfl_xor(idb, jl);
      const bool ogt = (ov > vb) || (ov == vb && oid > idb);
      if (ogt == keepMax) { vb = ov; idb = oid; }
    }
  };
  auto pairx = [&](int k) {
    const bool dir = (e0 & k) == 0;
    const bool bgt = (vb > va) || (vb == va && idb > ida);
    if (bgt != dir) {
      const float tv = va; va = vb; vb = tv;
      const int ti = ida; ida = idb; idb = ti;
    }
  };

#pragma unroll
  for (int k = 2; k <= 128; k <<= 1) {
#pragma unroll
    for (int j = k >> 1; j >= 2; j >>= 1) lanex(k, j);
    pairx(k);
  }
  v[e0] = va; id[e0] = ida;
  v[e1] = vb; id[e1] = idb;
  __syncthreads();

  for (int k = 256; k <= 2048; k <<= 1) {
    for (int j = k >> 1; j >= 128; j >>= 1) {
      const int i = ((tid & ~(j - 1)) << 1) | (tid & (j - 1));
      const int ixj = i | j;
      const bool up = (i & k) == 0;
      const float x0 = v[i], x1 = v[ixj];
      if (up ? (x0 > x1) : (x0 < x1)) {
        v[i] = x1;
        v[ixj] = x0;
        const int ti = id[i];
        id[i] = id[ixj];
        id[ixj] = ti;
      }
      __syncthreads();
    }
    va = v[e0]; ida = id[e0];
    vb = v[e1]; idb = id[e1];
#pragma unroll
    for (int j = 64; j >= 2; j >>= 1) lanex(k, j);
    pairx(k);
    v[e0] = va; id[e0] = ida;
    v[e1] = vb; id[e1] = idb;
    __syncthreads();
  }

  if (half == 1) {
    s1s[b * GAT_N + i0] = -v[i0];
    s1s[b * GAT_N + i1] = -v[i1];
    rids[b * GAT_N + i0] = id[i0];
    rids[b * GAT_N + i1] = id[i1];
    return;
  }
  s2s[b * GAT_N + i0] = v[i0];
  s2s[b * GAT_N + i1] = v[i1];
  idxs[b * GAT_N + i0] = id[i0];
  idxs[b * GAT_N + i1] = id[i1];

  const int w = tid >> 6;
  const float aL = __expf(GAT_ALPHA * v[2 * tid]);
  const float aR = __expf(GAT_ALPHA * v[2 * tid + 1]);
  const float pL = __expf(v[2047 - 2 * tid]);
  const float pR = __expf(v[2046 - 2 * tid]);
  wA[b * GAT_N + 2 * tid] = aL;
  wA[b * GAT_N + 2 * tid + 1] = aR;
  wP[b * GAT_N + 2047 - 2 * tid] = pL;
  wP[b * GAT_N + 2046 - 2 * tid] = pR;
  float sA = aL + aR, sP = pL + pR;
#pragma unroll
  for (int off = 1; off < 64; off <<= 1) {
    const float tA = __shfl_up(sA, off);
    const float tP = __shfl_up(sP, off);
    if (lane >= off) {
      sA += tA;
      sP += tP;
    }
  }
  if (lane == 63) {
    wtotA[w] = sA;
    wtotP[w] = sP;
  }
  __syncthreads();
  float offA = 0.f, offP = 0.f;
  for (int ww = 0; ww < w; ++ww) {
    offA += wtotA[ww];
    offP += wtotP[ww];
  }
  const float inclA = offA + sA;
  const float inclP = offP + sP;
  preDenA[b * GAT_N + 2 * tid] = inclA - aR;
  preDenA[b * GAT_N + 2 * tid + 1] = inclA;
  sufDenP[b * GAT_N + 2047 - 2 * tid] = inclP - pR;
  sufDenP[b * GAT_N + 2046 - 2 * tid] = inclP;
}

// ---------------------------------------------------------------------------
// K3: permute h into sorted order (hs[q] = h[idx[q]]) + CL=8 chunk partials.
// float2-wide: wave = one chunk (lane = 8B of the 512B row), block = 2 chunks.
// 2048 blocks x 128 threads. Same grid/traffic as R14, ~half the instructions.
// (This body ran correctly in R16; the fused tail was the regression there.)
// ---------------------------------------------------------------------------
__global__ __launch_bounds__(128) void k3_permute(const float* __restrict__ h,
                                                  const int* __restrict__ idxs,
                                                  const float* __restrict__ wA,
                                                  const float* __restrict__ wP,
                                                  float* __restrict__ hs,
                                                  float* __restrict__ partA,
                                                  float* __restrict__ partP) {
  const int b = blockIdx.x >> 7, cc = blockIdx.x & 127;
  const int t = threadIdx.x;
  const int w = t >> 6, l = t & 63;
  const int c = cc * 2 + w;  // each wave owns one chunk
  const int q0 = c * CL;
  const int* idxb = idxs + b * GAT_N;
  const float2* hb2 = (const float2*)(h + (size_t)b * GAT_N * GAT_D);
  float2* hs2 = (float2*)(hs + (size_t)b * GAT_N * GAT_D);
  float2 accA = make_float2(0.f, 0.f), accP = make_float2(0.f, 0.f);
#pragma unroll
  for (int qq = 0; qq < CL; ++qq) {
    const int q = q0 + qq;
    const int j = idxb[q];
    const float2 hv = hb2[(size_t)j * 64 + l];
    hs2[(size_t)q * 64 + l] = hv;
    const float wa = wA[b * GAT_N + q];
    const float wp = wP[b * GAT_N + q];
    accA.x = fmaf(wa, hv.x, accA.x);
    accA.y = fmaf(wa, hv.y, accA.y);
    accP.x = fmaf(wp, hv.x, accP.x);
    accP.y = fmaf(wp, hv.y, accP.y);
  }
  ((float2*)partA)[(size_t)(b * CH + c) * 64 + l] = accA;
  ((float2*)partP)[(size_t)(b * CH + c) * 64 + l] = accP;
}

// ---------------------------------------------------------------------------
// K3b: 32 blocks (2 per batch), 1024 threads.
//  role 0: scan chunk partials into exclusive prefix/suffix bases (reload-
//   based, 8 groups x 32 chunks).
//  role 1: per-row prep: binary search p (s2s in LDS), den from global
//   preDenA/sufDenP, c1=e1/den, c2=e2/den.  [R14, banked]
// ---------------------------------------------------------------------------
__global__ __launch_bounds__(1024) void k3b_prep(const float* __restrict__ s1s,
                                                 const float* __restrict__ s2s,
                                                 const float* __restrict__ preDenA,
                                                 const float* __restrict__ sufDenP,
                                                 const float* __restrict__ partA,
                                                 const float* __restrict__ partP,
                                                 float* __restrict__ baseA,
                                                 float* __restrict__ baseP,
                                                 int* __restrict__ pArr,
                                                 float* __restrict__ c1,
                                                 float* __restrict__ c2) {
  __shared__ float totA[8][128];
  __shared__ float totP[8][128];
  __shared__ float sh[2048];
  const int b = blockIdx.x >> 1;
  const int role = blockIdx.x & 1;
  const int t = threadIdx.x;
  if (role == 0) {
    const int d = t & 127, g = t >> 7;  // 8 groups x 32 chunks
    const float* pA = partA + (size_t)(b * CH + g * 32) * GAT_D + d;
    const float* pP = partP + (size_t)(b * CH + g * 32) * GAT_D + d;
    float sA = 0.f, sP = 0.f;
#pragma unroll 8
    for (int i = 0; i < 32; ++i) {
      sA += pA[i * GAT_D];
      sP += pP[i * GAT_D];
    }
    totA[g][d] = sA;
    totP[g][d] = sP;
    __syncthreads();
    float offA = 0.f, offP = 0.f;
    for (int gg = 0; gg < g; ++gg) offA += totA[gg][d];
    for (int gg = g + 1; gg < 8; ++gg) offP += totP[gg][d];
    float run = offA;
#pragma unroll 8
    for (int i = 0; i < 32; ++i) {
      baseA[(size_t)(b * (CH + 1) + g * 32 + i) * GAT_D + d] = run;
      run += pA[i * GAT_D];
    }
    if (g == 7) baseA[(size_t)(b * (CH + 1) + CH) * GAT_D + d] = run;
    run = offP;
#pragma unroll 8
    for (int i = 31; i >= 0; --i) {
      baseP[(size_t)(b * CH + g * 32 + i) * GAT_D + d] = run;
      run += pP[i * GAT_D];
    }
  } else {
    sh[t] = s2s[b * GAT_N + t];
    sh[t + 1024] = s2s[b * GAT_N + t + 1024];
    __syncthreads();
#pragma unroll
    for (int rr = 0; rr < 2; ++rr) {
      const int j = t + rr * 1024;
      const float s1v = s1s[b * GAT_N + j];
      const float tt = -s1v;
      int lo = 0, hi = GAT_N;
      while (lo < hi) {
        const int mid = (lo + hi) >> 1;
        if (sh[mid] < tt)
          lo = mid + 1;
        else
          hi = mid;
      }
      const float e1 = __expf(s1v), e2 = __expf(GAT_ALPHA * s1v);
      float den = 0.f;
      if (lo < GAT_N) den += e1 * sufDenP[b * GAT_N + lo];
      if (lo > 0) den += e2 * preDenA[b * GAT_N + lo - 1];
      const float inv = 1.f / den;
      pArr[b * GAT_N + j] = lo;
      c1[b * GAT_N + j] = e1 * inv;
      c2[b * GAT_N + j] = e2 * inv;
    }
  }
}

// ---------------------------------------------------------------------------
// K5: one wave per row (s1-sorted order for chunk locality). Combine chunk
// base + <=8-step within-chunk float2 cumsum over STREAMING hs, relu,
// scatter by original row id.  [R14, banked]
// ---------------------------------------------------------------------------
__global__ __launch_bounds__(256) void k5_out(const float* __restrict__ hs,
                                              const float* __restrict__ wA,
                                              const float* __restrict__ wP,
                                              const float* __restrict__ baseA,
                                              const float* __restrict__ baseP,
                                              const int* __restrict__ pArr,
                                              const float* __restrict__ c1,
                                              const float* __restrict__ c2,
                                              const int* __restrict__ rids,
                                              float* __restrict__ out) {
  const int wave = threadIdx.x >> 6, lane = threadIdx.x & 63;
  const int j = blockIdx.x * 4 + wave;  // sorted row index
  const int b = j >> 11;
  const int jr = b * GAT_N + (j & 2047);
  const int p = pArr[jr];
  const float cc1 = c1[jr], cc2 = c2[jr];
  const int rid = rids[jr];
  const float2* hs2 = (const float2*)(hs + (size_t)b * GAT_N * GAT_D);
  const float* wAb = wA + b * GAT_N;
  const float* wPb = wP + b * GAT_N;

  const int cA = p >> 3;
  float2 accA = ((const float2*)(baseA + (size_t)(b * (CH + 1) + cA) * GAT_D))[lane];
#pragma unroll 4
  for (int q = cA * CL; q < p; ++q) {
    const float w = wAb[q];
    const float2 hv = hs2[(size_t)q * 64 + lane];
    accA.x = fmaf(w, hv.x, accA.x);
    accA.y = fmaf(w, hv.y, accA.y);
  }

  const int pP = p < GAT_N ? p : GAT_N - 1;
  const int cP = pP >> 3;
  float2 accP = ((const float2*)(baseP + (size_t)(b * CH + cP) * GAT_D))[lane];
  const int qend = cP * CL + CL;
#pragma unroll 4
  for (int q = p; q < qend; ++q) {
    const float w = wPb[q];
    const float2 hv = hs2[(size_t)q * 64 + lane];
    accP.x = fmaf(w, hv.x, accP.x);
    accP.y = fmaf(w, hv.y, accP.y);
  }

  const float vx = cc2 * accA.x + cc1 * accP.x;
  const float vy = cc2 * accA.y + cc1 * accP.y;
  ((float2*)out)[(size_t)(b * GAT_N + rid) * 64 + lane] =
      make_float2(fmaxf(vx, 0.f), fmaxf(vy, 0.f));
}

extern "C" void kernel_launch(void* const* d_in, const int* in_sizes, int n_in,
                              void* d_out, int out_size, void* d_ws, size_t ws_size,
                              hipStream_t stream) {
  (void)in_sizes;
  (void)n_in;
  (void)out_size;
  (void)ws_size;
  const float* x = (const float*)d_in[0];
  const float* W = (const float*)d_in[1];
  const float* a = (const float*)d_in[2];
  float* out = (float*)d_out;
  float* wsf = (float*)d_ws;

  const size_t HN = (size_t)GAT_ROWS * GAT_D;
  size_t o = 0;
  float* s1part = wsf + o;   o += 4 * GAT_ROWS;
  float* s2part = wsf + o;   o += 4 * GAT_ROWS;
  float* s2s = wsf + o;      o += GAT_ROWS;
  int* idxs = (int*)(wsf + o); o += GAT_ROWS;
  float* s1s = wsf + o;      o += GAT_ROWS;
  int* rids = (int*)(wsf + o); o += GAT_ROWS;
  float* preDenA = wsf + o;  o += GAT_ROWS;
  float* sufDenP = wsf + o;  o += GAT_ROWS;
  float* wAr = wsf + o;      o += GAT_ROWS;
  float* wPr = wsf + o;      o += GAT_ROWS;
  int* pArr = (int*)(wsf + o); o += GAT_ROWS;
  float* c1 = wsf + o;       o += GAT_ROWS;
  float* c2 = wsf + o;       o += GAT_ROWS;
  float* partA = wsf + o;    o += (size_t)GAT_B * CH * GAT_D;
  float* partP = wsf + o;    o += (size_t)GAT_B * CH * GAT_D;
  float* baseA = wsf + o;    o += (size_t)GAT_B * (CH + 1) * GAT_D;
  float* baseP = wsf + o;    o += (size_t)GAT_B * CH * GAT_D;
  float* h = wsf + o;        o += HN;
  float* hs = wsf + o;       o += HN;

  k1_gemm<<<512, 256, 0, stream>>>(x, W, a, h, s1part, s2part);
  k2_sort<<<2 * GAT_B, 1024, 0, stream>>>(s1part, s2part, s2s, idxs, s1s, rids, wAr, wPr,
                                          preDenA, sufDenP);
  k3_permute<<<GAT_B * 128, 128, 0, stream>>>(h, idxs, wAr, wPr, hs, partA, partP);
  k3b_prep<<<2 * GAT_B, 1024, 0, stream>>>(s1s, s2s, preDenA, sufDenP, partA, partP,
                                           baseA, baseP, pArr, c1, c2);
  k5_out<<<GAT_ROWS / 4, 256, 0, stream>>>(hs, wAr, wPr, baseA, baseP, pArr, c1, c2,
                                           rids, out);
}

// Round 19
// 66.201 us; speedup vs baseline: 3.5679x; 1.0100x over previous
//
#include <hip/hip_runtime.h>
#include <hip/hip_bf16.h>
#include <cstddef>

#define GAT_B 16
#define GAT_N 2048
#define GAT_D 128
#define GAT_ROWS (GAT_B * GAT_N)
#define CH 256          // position-chunks per batch
#define CL 8            // positions per chunk
#define GAT_ALPHA 0.2f

typedef __attribute__((ext_vector_type(8))) short short8v;  // 8 bf16 (4 VGPRs)
typedef __attribute__((ext_vector_type(4))) float f32x4;

__device__ __forceinline__ void cvt_hilo(float x, unsigned short& hi, unsigned short& lo) {
  union { float f; unsigned u; } a;
  a.f = x;
  hi = (unsigned short)(a.u >> 16);
  union { unsigned u; float f; } b;
  b.u = (unsigned)hi << 16;
  union { float f; unsigned u; } c;
  c.f = x - b.f;
  lo = (unsigned short)(c.u >> 16);
}

// ---------------------------------------------------------------------------
// K1: h = x @ W via MFMA bf16 3-term split (x_hi*W_hi + x_lo*W_hi + x_hi*W_lo).
// 512 blocks x 256 threads (4 waves). Block tile 64 rows x 128 cols; wave =
// 64 rows x 32 cols. LDS 32KB (x hi/lo, XOR-swizzled). W read directly from
// global fp32 (L2-resident), converted in registers. [R14, banked]
// ---------------------------------------------------------------------------
__global__ __launch_bounds__(256) void k1_gemm(const float* __restrict__ x,
                                               const float* __restrict__ W,
                                               const float* __restrict__ aa,
                                               float* __restrict__ h,
                                               float* __restrict__ s1part,
                                               float* __restrict__ s2part) {
  __shared__ unsigned short xH[64 * 128];  // 16KB, [row][slot^row&7]
  __shared__ unsigned short xL[64 * 128];  // 16KB
  const int tid = threadIdx.x;
  const int row0 = blockIdx.x * 64;

#pragma unroll
  for (int p = 0; p < 8; ++p) {
    const int row = p * 8 + (tid >> 5);
    const int f4 = tid & 31;
    const float4 v = ((const float4*)(x + (size_t)(row0 + row) * GAT_D))[f4];
    unsigned short h0, h1, h2, h3, l0, l1, l2, l3;
    cvt_hilo(v.x, h0, l0);
    cvt_hilo(v.y, h1, l1);
    cvt_hilo(v.z, h2, l2);
    cvt_hilo(v.w, h3, l3);
    const int slot = (f4 >> 1) ^ (row & 7);
    const int base = row * 128 + slot * 8 + (f4 & 1) * 4;
    *(ushort4*)&xH[base] = make_ushort4(h0, h1, h2, h3);
    *(ushort4*)&xL[base] = make_ushort4(l0, l1, l2, l3);
  }

  const int w = tid >> 6, l = tid & 63;
  const int wc0 = w * 32;
  const int g = l >> 4, c16 = l & 15;

  short8v bh[4][2], bl[4][2];
#pragma unroll
  for (int ks = 0; ks < 4; ++ks)
#pragma unroll
    for (int nt = 0; nt < 2; ++nt) {
      const int n = wc0 + nt * 16 + c16;
#pragma unroll
      for (int j = 0; j < 8; ++j) {
        unsigned short hi, lo;
        cvt_hilo(W[(ks * 32 + g * 8 + j) * 128 + n], hi, lo);
        bh[ks][nt][j] = (short)hi;
        bl[ks][nt][j] = (short)lo;
      }
    }

  __syncthreads();

  f32x4 acc[4][2];
#pragma unroll
  for (int mt = 0; mt < 4; ++mt)
#pragma unroll
    for (int nt = 0; nt < 2; ++nt) acc[mt][nt] = (f32x4)(0.f);

#pragma unroll
  for (int ks = 0; ks < 4; ++ks) {
    short8v ah[4], al[4];
#pragma unroll
    for (int mt = 0; mt < 4; ++mt) {
      const int row = mt * 16 + c16;
      const int ai = row * 128 + (((ks * 4 + g) ^ (row & 7)) * 8);
      ah[mt] = *(const short8v*)&xH[ai];
      al[mt] = *(const short8v*)&xL[ai];
    }
#pragma unroll
    for (int mt = 0; mt < 4; ++mt) {
#pragma unroll
      for (int nt = 0; nt < 2; ++nt) {
        acc[mt][nt] = __builtin_amdgcn_mfma_f32_16x16x32_bf16(ah[mt], bh[ks][nt], acc[mt][nt], 0, 0, 0);
        acc[mt][nt] = __builtin_amdgcn_mfma_f32_16x16x32_bf16(al[mt], bh[ks][nt], acc[mt][nt], 0, 0, 0);
        acc[mt][nt] = __builtin_amdgcn_mfma_f32_16x16x32_bf16(ah[mt], bl[ks][nt], acc[mt][nt], 0, 0, 0);
      }
    }
  }

#pragma unroll
  for (int mt = 0; mt < 4; ++mt)
#pragma unroll
    for (int nt = 0; nt < 2; ++nt)
#pragma unroll
      for (int j = 0; j < 4; ++j)
        h[(size_t)(row0 + mt * 16 + g * 4 + j) * GAT_D + wc0 + nt * 16 + c16] =
            acc[mt][nt][j];

  float a1v[2], a2v[2];
#pragma unroll
  for (int nt = 0; nt < 2; ++nt) {
    a1v[nt] = aa[wc0 + nt * 16 + c16];
    a2v[nt] = aa[128 + wc0 + nt * 16 + c16];
  }
#pragma unroll
  for (int mt = 0; mt < 4; ++mt) {
#pragma unroll
    for (int j = 0; j < 4; ++j) {
      float t1 = acc[mt][0][j] * a1v[0] + acc[mt][1][j] * a1v[1];
      float t2 = acc[mt][0][j] * a2v[0] + acc[mt][1][j] * a2v[1];
#pragma unroll
      for (int off = 1; off < 16; off <<= 1) {
        t1 += __shfl_xor(t1, off);
        t2 += __shfl_xor(t2, off);
      }
      if (c16 == 0) {
        const int row = row0 + mt * 16 + g * 4 + j;
        s1part[w * GAT_ROWS + row] = t1;
        s2part[w * GAT_ROWS + row] = t2;
      }
    }
  }
}

// ---------------------------------------------------------------------------
// K2: 32 blocks (2 per batch), 1024 threads. Sums the 4 wave-partials of
// s1/s2 on load. HYBRID bitonic: k=2..128 in registers via shfl_xor;
// k=256..2048 LDS for j>=128 + register tail. ~15 barriers vs 66.
//  even block: sort s2 -> s2s/idxs, exp weights wA/wP, + den scans.
//  odd block:  sort key=-s1 -> s1s (desc) / rids.  [R14, banked]
// ---------------------------------------------------------------------------
__global__ __launch_bounds__(1024) void k2_sort(const float* __restrict__ s1part,
                                                const float* __restrict__ s2part,
                                                float* __restrict__ s2s,
                                                int* __restrict__ idxs,
                                                float* __restrict__ s1s,
                                                int* __restrict__ rids,
                                                float* __restrict__ wA,
                                                float* __restrict__ wP,
                                                float* __restrict__ preDenA,
                                                float* __restrict__ sufDenP) {
  __shared__ float v[2048];
  __shared__ int id[2048];
  __shared__ float wtotA[16];
  __shared__ float wtotP[16];
  const int tid = threadIdx.x;
  const int b = blockIdx.x >> 1;
  const int half = blockIdx.x & 1;
  const int i0 = tid, i1 = tid + 1024;
  const float* src = (half == 0) ? s2part : s1part;
  {
    const int r0 = b * GAT_N + i0, r1 = b * GAT_N + i1;
    float v0 = src[r0] + src[GAT_ROWS + r0] + src[2 * GAT_ROWS + r0] + src[3 * GAT_ROWS + r0];
    float v1 = src[r1] + src[GAT_ROWS + r1] + src[2 * GAT_ROWS + r1] + src[3 * GAT_ROWS + r1];
    if (half == 1) {
      v0 = -v0;
      v1 = -v1;
    }
    v[i0] = v0;
    v[i1] = v1;
  }
  __syncthreads();

  const int lane = tid & 63;
  const int e0 = ((tid >> 6) << 7) + lane * 2;  // wave-run base + 2*lane
  const int e1 = e0 + 1;
  float va = v[e0], vb = v[e1];
  int ida = e0, idb = e1;

  auto lanex = [&](int k, int j) {
    const int jl = j >> 1;
    const bool dir = (e0 & k) == 0;
    const bool lower = (lane & jl) == 0;
    const bool keepMax = lower ^ dir;
    {
      const float ov = __shfl_xor(va, jl);
      const int oid = __shfl_xor(ida, jl);
      const bool ogt = (ov > va) || (ov == va && oid > ida);
      if (ogt == keepMax) { va = ov; ida = oid; }
    }
    {
      const float ov = __shfl_xor(vb, jl);
      const int oid = __shfl_xor(idb, jl);
      const bool ogt = (ov > vb) || (ov == vb && oid > idb);
      if (ogt == keepMax) { vb = ov; idb = oid; }
    }
  };
  auto pairx = [&](int k) {
    const bool dir = (e0 & k) == 0;
    const bool bgt = (vb > va) || (vb == va && idb > ida);
    if (bgt != dir) {
      const float tv = va; va = vb; vb = tv;
      const int ti = ida; ida = idb; idb = ti;
    }
  };

#pragma unroll
  for (int k = 2; k <= 128; k <<= 1) {
#pragma unroll
    for (int j = k >> 1; j >= 2; j >>= 1) lanex(k, j);
    pairx(k);
  }
  v[e0] = va; id[e0] = ida;
  v[e1] = vb; id[e1] = idb;
  __syncthreads();

  for (int k = 256; k <= 2048; k <<= 1) {
    for (int j = k >> 1; j >= 128; j >>= 1) {
      const int i = ((tid & ~(j - 1)) << 1) | (tid & (j - 1));
      const int ixj = i | j;
      const bool up = (i & k) == 0;
      const float x0 = v[i], x1 = v[ixj];
      if (up ? (x0 > x1) : (x0 < x1)) {
        v[i] = x1;
        v[ixj] = x0;
        const int ti = id[i];
        id[i] = id[ixj];
        id[ixj] = ti;
      }
      __syncthreads();
    }
    va = v[e0]; ida = id[e0];
    vb = v[e1]; idb = id[e1];
#pragma unroll
    for (int j = 64; j >= 2; j >>= 1) lanex(k, j);
    pairx(k);
    v[e0] = va; id[e0] = ida;
    v[e1] = vb; id[e1] = idb;
    __syncthreads();
  }

  if (half == 1) {
    s1s[b * GAT_N + i0] = -v[i0];
    s1s[b * GAT_N + i1] = -v[i1];
    rids[b * GAT_N + i0] = id[i0];
    rids[b * GAT_N + i1] = id[i1];
    return;
  }
  s2s[b * GAT_N + i0] = v[i0];
  s2s[b * GAT_N + i1] = v[i1];
  idxs[b * GAT_N + i0] = id[i0];
  idxs[b * GAT_N + i1] = id[i1];

  const int w = tid >> 6;
  const float aL = __expf(GAT_ALPHA * v[2 * tid]);
  const float aR = __expf(GAT_ALPHA * v[2 * tid + 1]);
  const float pL = __expf(v[2047 - 2 * tid]);
  const float pR = __expf(v[2046 - 2 * tid]);
  wA[b * GAT_N + 2 * tid] = aL;
  wA[b * GAT_N + 2 * tid + 1] = aR;
  wP[b * GAT_N + 2047 - 2 * tid] = pL;
  wP[b * GAT_N + 2046 - 2 * tid] = pR;
  float sA = aL + aR, sP = pL + pR;
#pragma unroll
  for (int off = 1; off < 64; off <<= 1) {
    const float tA = __shfl_up(sA, off);
    const float tP = __shfl_up(sP, off);
    if (lane >= off) {
      sA += tA;
      sP += tP;
    }
  }
  if (lane == 63) {
    wtotA[w] = sA;
    wtotP[w] = sP;
  }
  __syncthreads();
  float offA = 0.f, offP = 0.f;
  for (int ww = 0; ww < w; ++ww) {
    offA += wtotA[ww];
    offP += wtotP[ww];
  }
  const float inclA = offA + sA;
  const float inclP = offP + sP;
  preDenA[b * GAT_N + 2 * tid] = inclA - aR;
  preDenA[b * GAT_N + 2 * tid + 1] = inclA;
  sufDenP[b * GAT_N + 2047 - 2 * tid] = inclP - pR;
  sufDenP[b * GAT_N + 2046 - 2 * tid] = inclP;
}

// ---------------------------------------------------------------------------
// K3: permute h into sorted order (hs[q] = h[idx[q]]) and partial sums of
// w*hs at CL=8 granularity. One block per (batch, 16 positions = 2 chunks),
// 128 threads. Gather-read of h happens exactly once here. [R14, banked]
// ---------------------------------------------------------------------------
__global__ __launch_bounds__(128) void k3_permute(const float* __restrict__ h,
                                                  const int* __restrict__ idxs,
                                                  const float* __restrict__ wA,
                                                  const float* __restrict__ wP,
                                                  float* __restrict__ hs,
                                                  float* __restrict__ partA,
                                                  float* __restrict__ partP) {
  const int b = blockIdx.x >> 7, cc = blockIdx.x & 127;
  const int d = threadIdx.x;
  const int* idxb = idxs + b * GAT_N;
  const float* hb = h + (size_t)b * GAT_N * GAT_D;
#pragma unroll
  for (int sub = 0; sub < 2; ++sub) {
    const int c = cc * 2 + sub;
    const int q0 = c * CL;
    float accA = 0.f, accP = 0.f;
#pragma unroll
    for (int qq = 0; qq < CL; ++qq) {
      const int q = q0 + qq;
      const int j = idxb[q];
      const float hv = hb[(size_t)j * GAT_D + d];
      hs[((size_t)b * GAT_N + q) * GAT_D + d] = hv;
      accA = fmaf(wA[b * GAT_N + q], hv, accA);
      accP = fmaf(wP[b * GAT_N + q], hv, accP);
    }
    partA[(b * CH + c) * GAT_D + d] = accA;
    partP[(b * CH + c) * GAT_D + d] = accP;
  }
}

// ---------------------------------------------------------------------------
// K3b: 32 blocks (2 per batch), 1024 threads.
//  role 0: scan chunk partials into exclusive prefix/suffix bases (reload-
//   based, 8 groups x 32 chunks -> no register arrays, VGPR-safe).
//  role 1: per-row prep: binary search p (s2s in LDS), den from global
//   preDenA/sufDenP, c1=e1/den, c2=e2/den.  [R14, banked]
// ---------------------------------------------------------------------------
__global__ __launch_bounds__(1024) void k3b_prep(const float* __restrict__ s1s,
                                                 const float* __restrict__ s2s,
                                                 const float* __restrict__ preDenA,
                                                 const float* __restrict__ sufDenP,
                                                 const float* __restrict__ partA,
                                                 const float* __restrict__ partP,
                                                 float* __restrict__ baseA,
                                                 float* __restrict__ baseP,
                                                 int* __restrict__ pArr,
                                                 float* __restrict__ c1,
                                                 float* __restrict__ c2) {
  __shared__ float totA[8][128];
  __shared__ float totP[8][128];
  __shared__ float sh[2048];
  const int b = blockIdx.x >> 1;
  const int role = blockIdx.x & 1;
  const int t = threadIdx.x;
  if (role == 0) {
    const int d = t & 127, g = t >> 7;  // 8 groups x 32 chunks
    const float* pA = partA + (size_t)(b * CH + g * 32) * GAT_D + d;
    const float* pP = partP + (size_t)(b * CH + g * 32) * GAT_D + d;
    float sA = 0.f, sP = 0.f;
#pragma unroll 8
    for (int i = 0; i < 32; ++i) {
      sA += pA[i * GAT_D];
      sP += pP[i * GAT_D];
    }
    totA[g][d] = sA;
    totP[g][d] = sP;
    __syncthreads();
    float offA = 0.f, offP = 0.f;
    for (int gg = 0; gg < g; ++gg) offA += totA[gg][d];
    for (int gg = g + 1; gg < 8; ++gg) offP += totP[gg][d];
    float run = offA;
#pragma unroll 8
    for (int i = 0; i < 32; ++i) {
      baseA[(size_t)(b * (CH + 1) + g * 32 + i) * GAT_D + d] = run;
      run += pA[i * GAT_D];
    }
    if (g == 7) baseA[(size_t)(b * (CH + 1) + CH) * GAT_D + d] = run;
    run = offP;
#pragma unroll 8
    for (int i = 31; i >= 0; --i) {
      baseP[(size_t)(b * CH + g * 32 + i) * GAT_D + d] = run;
      run += pP[i * GAT_D];
    }
  } else {
    sh[t] = s2s[b * GAT_N + t];
    sh[t + 1024] = s2s[b * GAT_N + t + 1024];
    __syncthreads();
#pragma unroll
    for (int rr = 0; rr < 2; ++rr) {
      const int j = t + rr * 1024;
      const float s1v = s1s[b * GAT_N + j];
      const float tt = -s1v;
      int lo = 0, hi = GAT_N;
      while (lo < hi) {
        const int mid = (lo + hi) >> 1;
        if (sh[mid] < tt)
          lo = mid + 1;
        else
          hi = mid;
      }
      const float e1 = __expf(s1v), e2 = __expf(GAT_ALPHA * s1v);
      float den = 0.f;
      if (lo < GAT_N) den += e1 * sufDenP[b * GAT_N + lo];
      if (lo > 0) den += e2 * preDenA[b * GAT_N + lo - 1];
      const float inv = 1.f / den;
      pArr[b * GAT_N + j] = lo;
      c1[b * GAT_N + j] = e1 * inv;
      c2[b * GAT_N + j] = e2 * inv;
    }
  }
}

// ---------------------------------------------------------------------------
// K5: one wave per row (s1-sorted order for chunk locality). Combine chunk
// base + <=8-step within-chunk float2 cumsum over STREAMING hs, relu,
// scatter by original row id.  [R14, banked]
// ---------------------------------------------------------------------------
__global__ __launch_bounds__(256) void k5_out(const float* __restrict__ hs,
                                              const float* __restrict__ wA,
                                              const float* __restrict__ wP,
                                              const float* __restrict__ baseA,
                                              const float* __restrict__ baseP,
                                              const int* __restrict__ pArr,
                                              const float* __restrict__ c1,
                                              const float* __restrict__ c2,
                                              const int* __restrict__ rids,
                                              float* __restrict__ out) {
  const int wave = threadIdx.x >> 6, lane = threadIdx.x & 63;
  const int j = blockIdx.x * 4 + wave;  // sorted row index
  const int b = j >> 11;
  const int jr = b * GAT_N + (j & 2047);
  const int p = pArr[jr];
  const float cc1 = c1[jr], cc2 = c2[jr];
  const int rid = rids[jr];
  const float2* hs2 = (const float2*)(hs + (size_t)b * GAT_N * GAT_D);
  const float* wAb = wA + b * GAT_N;
  const float* wPb = wP + b * GAT_N;

  const int cA = p >> 3;
  float2 accA = ((const float2*)(baseA + (size_t)(b * (CH + 1) + cA) * GAT_D))[lane];
#pragma unroll 4
  for (int q = cA * CL; q < p; ++q) {
    const float w = wAb[q];
    const float2 hv = hs2[(size_t)q * 64 + lane];
    accA.x = fmaf(w, hv.x, accA.x);
    accA.y = fmaf(w, hv.y, accA.y);
  }

  const int pP = p < GAT_N ? p : GAT_N - 1;
  const int cP = pP >> 3;
  float2 accP = ((const float2*)(baseP + (size_t)(b * CH + cP) * GAT_D))[lane];
  const int qend = cP * CL + CL;
#pragma unroll 4
  for (int q = p; q < qend; ++q) {
    const float w = wPb[q];
    const float2 hv = hs2[(size_t)q * 64 + lane];
    accP.x = fmaf(w, hv.x, accP.x);
    accP.y = fmaf(w, hv.y, accP.y);
  }

  const float vx = cc2 * accA.x + cc1 * accP.x;
  const float vy = cc2 * accA.y + cc1 * accP.y;
  ((float2*)out)[(size_t)(b * GAT_N + rid) * 64 + lane] =
      make_float2(fmaxf(vx, 0.f), fmaxf(vy, 0.f));
}

extern "C" void kernel_launch(void* const* d_in, const int* in_sizes, int n_in,
                              void* d_out, int out_size, void* d_ws, size_t ws_size,
                              hipStream_t stream) {
  (void)in_sizes;
  (void)n_in;
  (void)out_size;
  (void)ws_size;
  const float* x = (const float*)d_in[0];
  const float* W = (const float*)d_in[1];
  const float* a = (const float*)d_in[2];
  float* out = (float*)d_out;
  float* wsf = (float*)d_ws;

  const size_t HN = (size_t)GAT_ROWS * GAT_D;
  size_t o = 0;
  float* s1part = wsf + o;   o += 4 * GAT_ROWS;
  float* s2part = wsf + o;   o += 4 * GAT_ROWS;
  float* s2s = wsf + o;      o += GAT_ROWS;
  int* idxs = (int*)(wsf + o); o += GAT_ROWS;
  float* s1s = wsf + o;      o += GAT_ROWS;
  int* rids = (int*)(wsf + o); o += GAT_ROWS;
  float* preDenA = wsf + o;  o += GAT_ROWS;
  float* sufDenP = wsf + o;  o += GAT_ROWS;
  float* wAr = wsf + o;      o += GAT_ROWS;
  float* wPr = wsf + o;      o += GAT_ROWS;
  int* pArr = (int*)(wsf + o); o += GAT_ROWS;
  float* c1 = wsf + o;       o += GAT_ROWS;
  float* c2 = wsf + o;       o += GAT_ROWS;
  float* partA = wsf + o;    o += (size_t)GAT_B * CH * GAT_D;
  float* partP = wsf + o;    o += (size_t)GAT_B * CH * GAT_D;
  float* baseA = wsf + o;    o += (size_t)GAT_B * (CH + 1) * GAT_D;
  float* baseP = wsf + o;    o += (size_t)GAT_B * CH * GAT_D;
  float* h = wsf + o;        o += HN;
  float* hs = wsf + o;       o += HN;

  k1_gemm<<<512, 256, 0, stream>>>(x, W, a, h, s1part, s2part);
  k2_sort<<<2 * GAT_B, 1024, 0, stream>>>(s1part, s2part, s2s, idxs, s1s, rids, wAr, wPr,
                                          preDenA, sufDenP);
  k3_permute<<<GAT_B * 128, 128, 0, stream>>>(h, idxs, wAr, wPr, hs, partA, partP);
  k3b_prep<<<2 * GAT_B, 1024, 0, stream>>>(s1s, s2s, preDenA, sufDenP, partA, partP,
                                           baseA, baseP, pArr, c1, c2);
  k5_out<<<GAT_ROWS / 4, 256, 0, stream>>>(hs, wAr, wPr, baseA, baseP, pArr, c1, c2,
                                           rids, out);
}